// Round 2
// baseline (105.773 us; speedup 1.0000x reference)
//
#include <hip/hip_runtime.h>

// YOLOv1 loss: N=4096, S=14, B=2, D=30 (f32). Request-rate-bound -> fix with
// coalesced float4 loads staged to LDS. Each wave independently stages its own
// 64 cells (contiguous 7680 B per tensor) then computes one cell per lane.
// LDS cell stride = 31 floats (gcd(31,32)=1 -> conflict-free lane-strided reads).

constexpr int SS = 14;
constexpr int STRIDE = 31;   // LDS floats per cell
constexpr int WPB = 2;       // waves per block
constexpr int TPB = WPB * 64;

__global__ __launch_bounds__(TPB) void yolo_cells(
    const float* __restrict__ pred,
    const float* __restrict__ targ,
    float* __restrict__ sums)   // d_ws: 5 floats (raw sums)
{
    __shared__ float Lp[WPB][64 * STRIDE];
    __shared__ float Lt[WPB][64 * STRIDE];
    const int wave = threadIdx.x >> 6;
    const int lane = threadIdx.x & 63;
    const int cell0 = (blockIdx.x * WPB + wave) * 64;   // wave's first cell

    // ---- stage: 64 cells * 30 floats = 480 float4 per tensor, coalesced ----
    const float4* gp = reinterpret_cast<const float4*>(pred + (size_t)cell0 * 30);
    const float4* gt = reinterpret_cast<const float4*>(targ + (size_t)cell0 * 30);
    float* lp = Lp[wave];
    float* lt = Lt[wave];

#pragma unroll
    for (int i = 0; i < 8; ++i) {
        int idx = i * 64 + lane;          // float4 index within wave's chunk
        if (idx < 480) {
            float4 vp = gp[idx];
            float4 vt = gt[idx];
            int l = idx * 4;              // linear float index (0..1919), mult of 4
            int c = l / 30;               // cell within wave (magic-mul)
            int e = l - c * 30;           // element, even, 0..28
            int a = c * STRIDE + e;
            int o2 = (e == 28) ? 3 : 2;   // z/w cross into next cell when e==28
            lp[a]        = vp.x;
            lp[a + 1]    = vp.y;
            lp[a + o2]   = vp.z;
            lp[a + o2+1] = vp.w;
            // targ elements 5..9 are never read -> skip those LDS writes
            int ez = (e == 28) ? 0 : e + 2;
            if (e < 5 || e >= 10)        lt[a]        = vt.x;
            if (e + 1 < 5 || e + 1 >= 10) lt[a + 1]   = vt.y;
            if (ez < 5 || ez >= 10)      lt[a + o2]   = vt.z;
            if (ez + 1 < 5 || ez + 1 >= 10) lt[a + o2+1] = vt.w;
        }
    }
    __syncthreads();

    // ---- compute: one cell per lane, reads from LDS (conflict-free) ----
    const float* p = lp + lane * STRIDE;
    const float* t = lt + lane * STRIDE;
    const int cell = cell0 + lane;

    float s0, s1, s2, s3, s4;
    {
        int ij = cell % (SS * SS);
        float offx = (float)(ij % SS);    // off = (j, i): x = column
        float offy = (float)(ij / SS);

        float t0 = t[0], t1 = t[1], t2 = t[2], t3 = t[3], t4 = t[4];
        float m  = (t4 == 1.0f) ? 1.0f : 0.0f;
        float nm = (t4 == 0.0f) ? 1.0f : 0.0f;

        const float S = 14.0f;
        float tcx = t0 / S + offx / S;
        float tcy = t1 / S + offy / S;
        float thw = 0.5f * t2, thh = 0.5f * t3;
        float tx0 = tcx - thw, ty0 = tcy - thh;
        float tx1 = tcx + thw, ty1 = tcy + thh;
        float area_t = t2 * t3;

        float p0 = p[0], p1 = p[1], p2v = p[2], p3 = p[3], p4 = p[4];
        float p5 = p[5], p6 = p[6], p7 = p[7], p8 = p[8], p9 = p[9];

        float iou0, iou1;
        {
            float cx = p0 / S + offx / S, cy = p1 / S + offy / S;
            float hw = 0.5f * p2v, hh = 0.5f * p3;
            float x0 = cx - hw, y0 = cy - hh, x1 = cx + hw, y1 = cy + hh;
            float wx = fmaxf(fminf(tx1, x1) - fmaxf(tx0, x0), 0.f);
            float wy = fmaxf(fminf(ty1, y1) - fmaxf(ty0, y0), 0.f);
            float inter = wx * wy;
            iou0 = inter / (area_t + p2v * p3 - inter);
        }
        {
            float cx = p5 / S + offx / S, cy = p6 / S + offy / S;
            float hw = 0.5f * p7, hh = 0.5f * p8;
            float x0 = cx - hw, y0 = cy - hh, x1 = cx + hw, y1 = cy + hh;
            float wx = fmaxf(fminf(tx1, x1) - fmaxf(tx0, x0), 0.f);
            float wy = fmaxf(fminf(ty1, y1) - fmaxf(ty0, y0), 0.f);
            float inter = wx * wy;
            iou1 = inter / (area_t + p7 * p8 - inter);
        }

        int k = (iou1 > iou0) ? 1 : 0;    // argmax first-max tie-break
        float b0 = k ? p5 : p0, b1 = k ? p6 : p1;
        float b2 = k ? p7 : p2v, b3 = k ? p8 : p3, b4 = k ? p9 : p4;
        float biou = k ? iou1 : iou0;

        float d0 = t0 - b0, d1 = t1 - b1;
        s0 = m * (d0 * d0 + d1 * d1);

        float e0 = sqrtf(t2) - sqrtf(b2);
        float e1 = sqrtf(t3) - sqrtf(b3);
        s1 = m * (e0 * e0 + e1 * e1);

        float dc = biou - b4;
        s2 = m * dc * dc;

        float conf_other = k ? p4 : p9;
        s3 = nm * (p4 * p4 + p9 * p9) + m * conf_other * conf_other;

        float cls = 0.f;
#pragma unroll
        for (int c2 = 10; c2 < 30; ++c2) { float d = t[c2] - p[c2]; cls += d * d; }
        s4 = m * cls;
    }

    // ---- wave butterfly reduce ----
#pragma unroll
    for (int o = 32; o > 0; o >>= 1) {
        s0 += __shfl_down(s0, o);
        s1 += __shfl_down(s1, o);
        s2 += __shfl_down(s2, o);
        s3 += __shfl_down(s3, o);
        s4 += __shfl_down(s4, o);
    }

    __shared__ float red[WPB][5];
    if (lane == 0) {
        red[wave][0] = s0; red[wave][1] = s1; red[wave][2] = s2;
        red[wave][3] = s3; red[wave][4] = s4;
    }
    __syncthreads();
    if (threadIdx.x < 5) {
        float r = 0.f;
#pragma unroll
        for (int w = 0; w < WPB; ++w) r += red[w][threadIdx.x];
        atomicAdd(&sums[threadIdx.x], r);
    }
}

__global__ void yolo_final(const float* __restrict__ sums,
                           float* __restrict__ out, float invN)
{
    float xy     = sums[0] * 5.0f * invN;
    float wh     = sums[1] * 5.0f * invN;
    float cobj   = sums[2] * invN;
    float cnoobj = sums[3] * 0.5f * invN;
    float cls    = sums[4] * invN;
    out[0] = xy + wh + cobj + cnoobj + cls;
    out[1] = xy;
    out[2] = wh;
    out[3] = cobj;
    out[4] = cnoobj;
    out[5] = cls;
}

extern "C" void kernel_launch(void* const* d_in, const int* in_sizes, int n_in,
                              void* d_out, int out_size, void* d_ws, size_t ws_size,
                              hipStream_t stream)
{
    const float* pred = (const float*)d_in[0];
    const float* targ = (const float*)d_in[1];
    int ncells = in_sizes[0] / 30;          // N * S * S = 802816
    int N = ncells / (SS * SS);
    float* sums = (float*)d_ws;

    hipMemsetAsync(sums, 0, 5 * sizeof(float), stream);

    int grid = ncells / (WPB * 64);         // 802816 / 128 = 6272 exact
    yolo_cells<<<grid, TPB, 0, stream>>>(pred, targ, sums);
    yolo_final<<<1, 1, 0, stream>>>(sums, (float*)d_out, 1.0f / (float)N);
}

// Round 3
// 68.273 us; speedup vs baseline: 1.5493x; 1.5493x over previous
//
#include <hip/hip_runtime.h>

// YOLOv1 loss, split by data layout:
//  A) box losses (pred[0..9], targ[0..4]) - one cell per thread, scattered loads
//  B) class loss (elems 10..29)           - fully coalesced float4 stream
//  C) final reduce of per-block partials  - no atomics anywhere (round-2 lesson:
//     31k same-line atomicAdds serialized ~100us at the TCC).

constexpr int SS = 14;

// ---------------- Kernel A: box losses ----------------
__global__ __launch_bounds__(256) void yolo_box(
    const float* __restrict__ pred,
    const float* __restrict__ targ,
    float4* __restrict__ partA,      // one float4(s_xy, s_wh, s_obj, s_noobj) per block
    int ncells)
{
    float s0 = 0.f, s1 = 0.f, s2 = 0.f, s3 = 0.f;
    const int stride = gridDim.x * 256;

    for (int cell = blockIdx.x * 256 + threadIdx.x; cell < ncells; cell += stride) {
        const float2* pc = reinterpret_cast<const float2*>(pred + (size_t)cell * 30);
        const float2* tc = reinterpret_cast<const float2*>(targ + (size_t)cell * 30);
        float2 a0 = pc[0], a1 = pc[1], a2 = pc[2], a3 = pc[3], a4 = pc[4];
        float2 b0 = tc[0], b1 = tc[1], b2 = tc[2];
        float p0=a0.x, p1=a0.y, p2=a1.x, p3=a1.y, p4=a2.x;
        float p5=a2.y, p6=a3.x, p7=a3.y, p8=a4.x, p9=a4.y;
        float t0=b0.x, t1=b0.y, t2=b1.x, t3=b1.y, t4=b2.x;

        int ij = cell % (SS * SS);
        float offx = (float)(ij % SS);   // off = (j, i): x = column
        float offy = (float)(ij / SS);

        float m  = (t4 == 1.0f) ? 1.0f : 0.0f;
        float nm = (t4 == 0.0f) ? 1.0f : 0.0f;

        const float S = 14.0f;
        float tcx = t0 / S + offx / S;
        float tcy = t1 / S + offy / S;
        float thw = 0.5f * t2, thh = 0.5f * t3;
        float tx0 = tcx - thw, ty0 = tcy - thh;
        float tx1 = tcx + thw, ty1 = tcy + thh;
        float area_t = t2 * t3;

        float iou0, iou1;
        {
            float cx = p0 / S + offx / S, cy = p1 / S + offy / S;
            float hw = 0.5f * p2, hh = 0.5f * p3;
            float x0 = cx - hw, y0 = cy - hh, x1 = cx + hw, y1 = cy + hh;
            float wx = fmaxf(fminf(tx1, x1) - fmaxf(tx0, x0), 0.f);
            float wy = fmaxf(fminf(ty1, y1) - fmaxf(ty0, y0), 0.f);
            float inter = wx * wy;
            iou0 = inter / (area_t + p2 * p3 - inter);
        }
        {
            float cx = p5 / S + offx / S, cy = p6 / S + offy / S;
            float hw = 0.5f * p7, hh = 0.5f * p8;
            float x0 = cx - hw, y0 = cy - hh, x1 = cx + hw, y1 = cy + hh;
            float wx = fmaxf(fminf(tx1, x1) - fmaxf(tx0, x0), 0.f);
            float wy = fmaxf(fminf(ty1, y1) - fmaxf(ty0, y0), 0.f);
            float inter = wx * wy;
            iou1 = inter / (area_t + p7 * p8 - inter);
        }

        int k = (iou1 > iou0) ? 1 : 0;   // jnp.argmax first-max tie-break
        float b0x = k ? p5 : p0, b1x = k ? p6 : p1;
        float b2x = k ? p7 : p2, b3x = k ? p8 : p3, b4x = k ? p9 : p4;
        float biou = k ? iou1 : iou0;

        float d0 = t0 - b0x, d1 = t1 - b1x;
        s0 += m * (d0 * d0 + d1 * d1);

        float e0 = sqrtf(t2) - sqrtf(b2x);
        float e1 = sqrtf(t3) - sqrtf(b3x);
        s1 += m * (e0 * e0 + e1 * e1);

        float dc = biou - b4x;
        s2 += m * dc * dc;

        float conf_other = k ? p4 : p9;
        s3 += nm * (p4 * p4 + p9 * p9) + m * conf_other * conf_other;
    }

    // wave butterfly reduce (64 lanes)
#pragma unroll
    for (int o = 32; o > 0; o >>= 1) {
        s0 += __shfl_down(s0, o);
        s1 += __shfl_down(s1, o);
        s2 += __shfl_down(s2, o);
        s3 += __shfl_down(s3, o);
    }
    __shared__ float4 red[4];
    int wave = threadIdx.x >> 6;
    if ((threadIdx.x & 63) == 0) red[wave] = make_float4(s0, s1, s2, s3);
    __syncthreads();
    if (threadIdx.x == 0) {
        float4 r = red[0];
        r.x += red[1].x + red[2].x + red[3].x;
        r.y += red[1].y + red[2].y + red[3].y;
        r.z += red[1].z + red[2].z + red[3].z;
        r.w += red[1].w + red[2].w + red[3].w;
        partA[blockIdx.x] = r;
    }
}

// ---------------- Kernel B: class loss, coalesced ----------------
__global__ __launch_bounds__(256) void yolo_cls(
    const float* __restrict__ pred,
    const float* __restrict__ targ,
    float* __restrict__ partB,       // one float per block
    int nf4)
{
    float acc = 0.f;
    const int stride = gridDim.x * 256;
    const float4* P = reinterpret_cast<const float4*>(pred);
    const float4* T = reinterpret_cast<const float4*>(targ);

    for (int q = blockIdx.x * 256 + threadIdx.x; q < nf4; q += stride) {
        int l  = q * 4;
        int c0 = l / 30;               // magic-mul
        int e0 = l - c0 * 30;          // even, 0..28
        float4 pv = P[q];
        float4 tv = T[q];
        float t4 = targ[l - e0 + 4];   // cell's objectness (L1-hot: inside streamed lines)
        float m  = (t4 == 1.0f) ? 1.0f : 0.0f;

        // elements e0..e0+3; wrap (e>=30) lands on next cell's box elems -> excluded
        float sum = 0.f;
        float d;
        d = tv.x - pv.x; if ((unsigned)(e0 + 0 - 10) < 20u) sum += d * d;
        d = tv.y - pv.y; if ((unsigned)(e0 + 1 - 10) < 20u) sum += d * d;
        d = tv.z - pv.z; if ((unsigned)(e0 + 2 - 10) < 20u) sum += d * d;
        d = tv.w - pv.w; if ((unsigned)(e0 + 3 - 10) < 20u) sum += d * d;
        acc += m * sum;
    }

#pragma unroll
    for (int o = 32; o > 0; o >>= 1) acc += __shfl_down(acc, o);
    __shared__ float red[4];
    int wave = threadIdx.x >> 6;
    if ((threadIdx.x & 63) == 0) red[wave] = acc;
    __syncthreads();
    if (threadIdx.x == 0)
        partB[blockIdx.x] = red[0] + red[1] + red[2] + red[3];
}

// ---------------- Kernel C: final reduce ----------------
__global__ __launch_bounds__(256) void yolo_final(
    const float4* __restrict__ partA, int nA,
    const float* __restrict__ partB, int nB,
    float* __restrict__ out, float invN)
{
    float a0 = 0.f, a1 = 0.f, a2 = 0.f, a3 = 0.f, b = 0.f;
    for (int i = threadIdx.x; i < nA; i += 256) {
        float4 v = partA[i];
        a0 += v.x; a1 += v.y; a2 += v.z; a3 += v.w;
    }
    for (int i = threadIdx.x; i < nB; i += 256) b += partB[i];

#pragma unroll
    for (int o = 32; o > 0; o >>= 1) {
        a0 += __shfl_down(a0, o);
        a1 += __shfl_down(a1, o);
        a2 += __shfl_down(a2, o);
        a3 += __shfl_down(a3, o);
        b  += __shfl_down(b, o);
    }
    __shared__ float red[4][5];
    int wave = threadIdx.x >> 6;
    if ((threadIdx.x & 63) == 0) {
        red[wave][0] = a0; red[wave][1] = a1; red[wave][2] = a2;
        red[wave][3] = a3; red[wave][4] = b;
    }
    __syncthreads();
    if (threadIdx.x == 0) {
        float xy     = (red[0][0]+red[1][0]+red[2][0]+red[3][0]) * 5.0f * invN;
        float wh     = (red[0][1]+red[1][1]+red[2][1]+red[3][1]) * 5.0f * invN;
        float cobj   = (red[0][2]+red[1][2]+red[2][2]+red[3][2]) * invN;
        float cnoobj = (red[0][3]+red[1][3]+red[2][3]+red[3][3]) * 0.5f * invN;
        float cls    = (red[0][4]+red[1][4]+red[2][4]+red[3][4]) * invN;
        out[0] = xy + wh + cobj + cnoobj + cls;
        out[1] = xy;
        out[2] = wh;
        out[3] = cobj;
        out[4] = cnoobj;
        out[5] = cls;
    }
}

extern "C" void kernel_launch(void* const* d_in, const int* in_sizes, int n_in,
                              void* d_out, int out_size, void* d_ws, size_t ws_size,
                              hipStream_t stream)
{
    const float* pred = (const float*)d_in[0];
    const float* targ = (const float*)d_in[1];
    int ncells = in_sizes[0] / 30;           // N*S*S = 802816
    int nf4    = in_sizes[0] / 4;            // 6021120
    int N      = ncells / (SS * SS);

    int gridA = 2048, gridB = 2048;
    if (ws_size < (size_t)(gridA * 16 + gridB * 4)) { gridA = 256; gridB = 256; }

    float4* partA = (float4*)d_ws;
    float*  partB = (float*)((char*)d_ws + (size_t)gridA * sizeof(float4));

    yolo_box<<<gridA, 256, 0, stream>>>(pred, targ, partA, ncells);
    yolo_cls<<<gridB, 256, 0, stream>>>(pred, targ, partB, nf4);
    yolo_final<<<1, 256, 0, stream>>>(partA, gridA, partB, gridB,
                                      (float*)d_out, 1.0f / (float)N);
}